// Round 1
// baseline (658.272 us; speedup 1.0000x reference)
//
#include <hip/hip_runtime.h>
#include <hip/hip_bf16.h>

// MoE top-1, N=4096 tokens, D=768, E=8, H=7680, O=768.
// Strategy: gate -> group tokens by expert -> two grouped bf16-MFMA GEMMs.
// Only the top-1 expert per token is computed (reference zeroes the rest).

#define N_TOK 4096
#define DIM   768
#define NE    8
#define HDIM  7680
#define ODIM  768

typedef __bf16 bf16x8 __attribute__((ext_vector_type(8)));
typedef float f32x4 __attribute__((ext_vector_type(4)));

// Manual RNE float->bf16 (no API-surface risk).
__device__ __forceinline__ unsigned short f2bf(float f) {
    union { float f; unsigned u; } v; v.f = f;
    unsigned r = (v.u + 0x7fffu + ((v.u >> 16) & 1u)) >> 16;
    return (unsigned short)r;
}

// ---------------- gating ----------------
// One wave per token. fp64 accumulation so our logits are near-exact; argmax
// tie-breaking = first max (matches lax.top_k). p = softmax prob of argmax.
// TIER encodes ws_size in the kernel name (rocprof probe; behavior identical).
template<int TIER>
__global__ void moe_gating(const float* __restrict__ x, const float* __restrict__ Wg,
                           const float* __restrict__ bg, int* __restrict__ cnt,
                           int* __restrict__ top_e, int* __restrict__ rnk,
                           float* __restrict__ top_p) {
    const int wid  = threadIdx.x >> 6;
    const int lane = threadIdx.x & 63;
    const int t = blockIdx.x * 4 + wid;
    double p[NE];
#pragma unroll
    for (int j = 0; j < NE; ++j) p[j] = 0.0;
    const float* xr  = x  + (size_t)t * DIM + lane * 12;
    const float* wr0 = Wg + lane * 12 * NE;
#pragma unroll
    for (int i = 0; i < 12; ++i) {
        double xv = (double)xr[i];
#pragma unroll
        for (int j = 0; j < NE; ++j) p[j] += xv * (double)wr0[i * NE + j];
    }
#pragma unroll
    for (int off = 32; off >= 1; off >>= 1) {
#pragma unroll
        for (int j = 0; j < NE; ++j) p[j] += __shfl_xor(p[j], off, 64);
    }
    if (lane == 0) {
        double l[NE];
#pragma unroll
        for (int j = 0; j < NE; ++j) l[j] = p[j] + (double)bg[j];
        int be = 0; double bl = l[0];
#pragma unroll
        for (int j = 1; j < NE; ++j) if (l[j] > bl) { bl = l[j]; be = j; }
        double s = 0.0;
#pragma unroll
        for (int j = 0; j < NE; ++j) s += exp(l[j] - bl);
        int rk = atomicAdd(&cnt[be], 1);
        top_e[t] = be; rnk[t] = rk; top_p[t] = (float)(1.0 / s);
    }
}

__global__ void moe_init(int* cnt) { if (threadIdx.x < NE) cnt[threadIdx.x] = 0; }

__global__ void moe_scan(const int* __restrict__ cnt, int* __restrict__ offs) {
    if (threadIdx.x == 0) { int s = 0; for (int e = 0; e < NE; ++e) { offs[e] = s; s += cnt[e]; } }
}

__global__ void moe_mkperm(const int* __restrict__ top_e, const int* __restrict__ rnk,
                           const float* __restrict__ top_p, const int* __restrict__ offs,
                           int* __restrict__ perm, float* __restrict__ gate_s) {
    int t = blockIdx.x * 256 + threadIdx.x;
    int e = top_e[t];
    int slot = offs[e] + rnk[t];
    perm[slot] = t;
    gate_s[slot] = top_p[t];
}

// Gather x rows into expert-grouped order, converting to bf16.
__global__ void moe_gather(const float* __restrict__ x, const int* __restrict__ perm,
                           unsigned short* __restrict__ Xg) {
    int slot = blockIdx.x;
    int t = perm[slot];
    const float* src = x + (size_t)t * DIM;
    unsigned short* dst = Xg + (size_t)slot * DIM;
    for (int i = threadIdx.x; i < DIM; i += 256) dst[i] = f2bf(src[i]);
}

// ---------------- grouped GEMM ----------------
// LAYER==1: H = relu(Xg @ W1[e] + b1[e])  (A=Xg bf16 [4096,768], B=W1 fp32 [768,7680])
// LAYER==2: out[perm] = gate * (H @ W2[e] + b2[e])  (A=H bf16 [4096,7680], B=W2 fp32 [7680,768])
// Block: 256 thr (4 waves, 2x2), tile 128x128, BK=32, mfma_f32_16x16x32_bf16.
// A LDS stride 40 ushorts (80B) -> b128 frag reads ~2-way (free).
// B LDS k-major stride 138 ushorts (276B) -> u16 frag reads spread groups by 8 banks (free).
// B staged from fp32 global (coalesced 256B/instr) with on-the-fly bf16 convert.
template<int LAYER>
__global__ __launch_bounds__(256) void moe_gemm(
    const unsigned short* __restrict__ A, const float* __restrict__ B,
    const float* __restrict__ bias, const int* __restrict__ cnt,
    const int* __restrict__ offs, const int* __restrict__ perm,
    const float* __restrict__ gate_s, unsigned short* __restrict__ H,
    float* __restrict__ out) {
    constexpr int KT  = (LAYER == 1) ? DIM  : HDIM;
    constexpr int NT  = (LAYER == 1) ? HDIM : ODIM;
    constexpr int AST = (LAYER == 1) ? DIM  : HDIM;

    const int e  = blockIdx.z;
    const int ne = cnt[e];
    const int mt = blockIdx.y;
    if (mt * 128 >= ne) return;             // empty / out-of-range tile
    const int base = offs[e];
    const int n0 = blockIdx.x * 128;
    const int mlim = ne - mt * 128;         // >= 1 valid rows in this tile

    __shared__ unsigned short Al[128 * 40];
    __shared__ unsigned short Bl[32 * 138];

    const float* Be = B + (size_t)e * KT * NT;
    const int tid = threadIdx.x;
    const int lane = tid & 63, wid = tid >> 6;
    const int wr = wid >> 1, wc = wid & 1;
    const int g = lane >> 4, r = lane & 15;

    f32x4 acc[4][4] = {};

    const int sbn = tid & 127;              // B staging: column within tile
    const int sbk = (tid >> 7) * 16;        // B staging: k base (0 or 16)

    for (int k0 = 0; k0 < KT; k0 += 32) {
        __syncthreads();                    // protect LDS from previous iter readers
        // stage A: 128x32 bf16, 16B per load, rows clamped to valid range
#pragma unroll
        for (int i = 0; i < 2; ++i) {
            int idx = tid + i * 256;
            int row = idx >> 2;
            int c8 = (idx & 3) << 3;
            int lr = row < mlim ? row : mlim - 1;
            const unsigned short* src = A + (size_t)(base + mt * 128 + lr) * AST + (k0 + c8);
            *(uint4*)(&Al[row * 40 + c8]) = *(const uint4*)src;
        }
        // stage B: 32x128 fp32 -> bf16, k-major in LDS
        {
            const float* bp = Be + (size_t)(k0 + sbk) * NT + (n0 + sbn);
            unsigned short* bw = &Bl[sbk * 138 + sbn];
#pragma unroll
            for (int i = 0; i < 16; ++i) bw[i * 138] = f2bf(bp[(size_t)i * NT]);
        }
        __syncthreads();
        // compute: per wave 4x4 fragments of 16x16, one mfma consumes K=32
        bf16x8 af[4];
#pragma unroll
        for (int m = 0; m < 4; ++m)
            af[m] = *(const bf16x8*)(&Al[(wr * 64 + m * 16 + r) * 40 + g * 8]);
#pragma unroll
        for (int n = 0; n < 4; ++n) {
            union { bf16x8 v; unsigned short u[8]; } bu;
            const unsigned short* bq = &Bl[(g * 8) * 138 + (wc * 64 + n * 16 + r)];
#pragma unroll
            for (int j = 0; j < 8; ++j) bu.u[j] = bq[j * 138];
#pragma unroll
            for (int m = 0; m < 4; ++m)
                acc[m][n] = __builtin_amdgcn_mfma_f32_16x16x32_bf16(af[m], bu.v, acc[m][n], 0, 0, 0);
        }
    }

    // epilogue: C/D layout col = lane&15, row = 4*(lane>>4) + reg  [m89-verified]
#pragma unroll
    for (int m = 0; m < 4; ++m) {
#pragma unroll
        for (int n = 0; n < 4; ++n) {
#pragma unroll
            for (int j = 0; j < 4; ++j) {
                int lrow = mt * 128 + wr * 64 + m * 16 + g * 4 + j;   // row local to expert
                if (lrow < ne) {
                    int col = n0 + wc * 64 + n * 16 + r;
                    float v = acc[m][n][j] + bias[(size_t)e * NT + col];
                    if constexpr (LAYER == 1) {
                        v = fmaxf(v, 0.0f);
                        H[(size_t)(base + lrow) * HDIM + col] = f2bf(v);
                    } else {
                        int slot = base + lrow;
                        out[(size_t)perm[slot] * ODIM + col] = gate_s[slot] * v;
                    }
                }
            }
        }
    }
}

// ---------------- launch ----------------
extern "C" void kernel_launch(void* const* d_in, const int* in_sizes, int n_in,
                              void* d_out, int out_size, void* d_ws, size_t ws_size,
                              hipStream_t stream) {
    const float* x  = (const float*)d_in[0];
    const float* Wg = (const float*)d_in[1];
    const float* bg = (const float*)d_in[2];
    const float* W1 = (const float*)d_in[3];
    const float* b1 = (const float*)d_in[4];
    const float* W2 = (const float*)d_in[5];
    const float* b2 = (const float*)d_in[6];
    float* out = (float*)d_out;

    char* ws = (char*)d_ws;
    int*   cnt    = (int*)(ws + 0);
    int*   offs   = (int*)(ws + 64);
    int*   top_e  = (int*)(ws + 128);
    int*   rnk    = (int*)(ws + 128 + 16384);
    float* top_p  = (float*)(ws + 128 + 2 * 16384);
    int*   perm   = (int*)(ws + 128 + 3 * 16384);
    float* gate_s = (float*)(ws + 128 + 4 * 16384);
    unsigned short* Xg = (unsigned short*)(ws + 82048);                       // 4096x768 bf16
    unsigned short* H  = (unsigned short*)(ws + 82048 + (size_t)N_TOK * DIM * 2); // 4096x7680 bf16
    // total ws need: ~66.1 MB

    moe_init<<<1, 64, 0, stream>>>(cnt);

    // ws_size probe via kernel name (behavior identical for all tiers)
    int tier;
    if      (ws_size >= (512ull << 20)) tier = 4;
    else if (ws_size >= (384ull << 20)) tier = 3;
    else if (ws_size >= (256ull << 20)) tier = 2;
    else if (ws_size >= (128ull << 20)) tier = 1;
    else                                 tier = 0;
    switch (tier) {
        case 4: moe_gating<4><<<N_TOK / 4, 256, 0, stream>>>(x, Wg, bg, cnt, top_e, rnk, top_p); break;
        case 3: moe_gating<3><<<N_TOK / 4, 256, 0, stream>>>(x, Wg, bg, cnt, top_e, rnk, top_p); break;
        case 2: moe_gating<2><<<N_TOK / 4, 256, 0, stream>>>(x, Wg, bg, cnt, top_e, rnk, top_p); break;
        case 1: moe_gating<1><<<N_TOK / 4, 256, 0, stream>>>(x, Wg, bg, cnt, top_e, rnk, top_p); break;
        default: moe_gating<0><<<N_TOK / 4, 256, 0, stream>>>(x, Wg, bg, cnt, top_e, rnk, top_p); break;
    }

    moe_scan<<<1, 64, 0, stream>>>(cnt, offs);
    moe_mkperm<<<N_TOK / 256, 256, 0, stream>>>(top_e, rnk, top_p, offs, perm, gate_s);
    moe_gather<<<N_TOK, 256, 0, stream>>>(x, perm, Xg);

    moe_gemm<1><<<dim3(HDIM / 128, N_TOK / 128, NE), 256, 0, stream>>>(
        Xg, W1, b1, cnt, offs, perm, gate_s, H, out);
    moe_gemm<2><<<dim3(ODIM / 128, N_TOK / 128, NE), 256, 0, stream>>>(
        H, W2, b2, cnt, offs, perm, gate_s, H, out);
}